// Round 9
// baseline (369.893 us; speedup 1.0000x reference)
//
#include <hip/hip_runtime.h>
#include <math.h>

#define NN 50000
#define NE 800000
#define NR 16
#define NBC 782                          // dst buckets of 64 nodes: ceil(50000/64)
#define ABLK 256                         // blocks in count/scatter passes
#define CHUNK ((NE + ABLK - 1) / ABLK)   // 3125

typedef __attribute__((ext_vector_type(8))) short short8;
typedef __attribute__((ext_vector_type(4))) float floatx4;

__device__ __forceinline__ unsigned short f2bf(float x) {
    unsigned int u = __float_as_uint(x);
    u += 0x7fffu + ((u >> 16) & 1u);
    return (unsigned short)(u >> 16);
}
__device__ __forceinline__ float bf2f(unsigned short s) {
    return __uint_as_float(((unsigned int)s) << 16);
}

// ---------------------------------------------------------------------------
// K1 (fused): blocks [0,196) init | [196,212) frag prep | [212,468) count.
//   init:  init_fea = concat(feat, embed[idx]) @ T -> out[:,0,:] + bf16 copy
//   prep:  wfragB = PER-BASIS bf16 B-fragments (msg = sum_b w_comp[t,b]*(x@Wb))
//          afrag (A_w halves), aproj[t] = A_b + attn_emb[t] @ A_w[64:]
//   count: per-block LDS histogram of dst>>6 -> cpb_t[bin][block] (plain
//          stores; zero global atomics — R6's 32B-write-through lesson)
// ---------------------------------------------------------------------------
__global__ void __launch_bounds__(256) k_phase1(
    const float* __restrict__ feat, const float* __restrict__ emb,
    const float* __restrict__ T, const int* __restrict__ idx,
    const float* __restrict__ weight, const float* __restrict__ A_w,
    const float* __restrict__ A_b, const float* __restrict__ attn_emb,
    const int* __restrict__ ed,
    float* __restrict__ out, unsigned short* __restrict__ init_bf,
    unsigned short* __restrict__ wfragB, unsigned short* __restrict__ afrag,
    float* __restrict__ aproj, int* __restrict__ cpb_t) {
    __shared__ int lc[NBC];
    const int b = blockIdx.x, tid = threadIdx.x;
    if (b < 196) {                                  // ---- init ----
        int i = b * 256 + tid;
        if (i >= NN) return;
        float v[32], acc[32];
#pragma unroll
        for (int o = 0; o < 32; o++) acc[o] = 0.f;
        const float4* fp = (const float4*)(feat + (size_t)i * 32);
#pragma unroll
        for (int q = 0; q < 8; q++) {
            float4 f = fp[q];
            v[4 * q] = f.x; v[4 * q + 1] = f.y; v[4 * q + 2] = f.z; v[4 * q + 3] = f.w;
        }
#pragma unroll
        for (int d = 0; d < 32; d++) {
            float xd = v[d];
#pragma unroll
            for (int o = 0; o < 32; o++) acc[o] += xd * T[d * 32 + o];
        }
        int row = idx[i];
        const float4* ep = (const float4*)(emb + (size_t)row * 32);
#pragma unroll
        for (int q = 0; q < 8; q++) {
            float4 f = ep[q];
            v[4 * q] = f.x; v[4 * q + 1] = f.y; v[4 * q + 2] = f.z; v[4 * q + 3] = f.w;
        }
#pragma unroll
        for (int d = 0; d < 32; d++) {
            float xd = v[d];
#pragma unroll
            for (int o = 0; o < 32; o++) acc[o] += xd * T[(32 + d) * 32 + o];
        }
        float4* op = (float4*)(out + (size_t)i * 64);
#pragma unroll
        for (int q = 0; q < 8; q++) {
            float4 f;
            f.x = acc[4 * q]; f.y = acc[4 * q + 1]; f.z = acc[4 * q + 2]; f.w = acc[4 * q + 3];
            op[q] = f;
        }
        unsigned int w[16];
#pragma unroll
        for (int q = 0; q < 16; q++)
            w[q] = (unsigned int)f2bf(acc[2 * q]) | ((unsigned int)f2bf(acc[2 * q + 1]) << 16);
        uint4* bp = (uint4*)(init_bf + (size_t)i * 32);
#pragma unroll
        for (int q = 0; q < 4; q++) {
            uint4 u; u.x = w[4 * q]; u.y = w[4 * q + 1]; u.z = w[4 * q + 2]; u.w = w[4 * q + 3];
            bp[q] = u;
        }
    } else if (b < 212) {                           // ---- prep ----
        int g = (b - 196) * 256 + tid;
        if (g < 4 * 1024) {                         // wfragB: 4096 (1024/basis)
            int bb = g >> 10, rest = g & 1023;
            int h = rest >> 9, l = (rest >> 3) & 63, j = rest & 7;
            int k = (l >> 4) * 8 + j, n = (l & 15) + 16 * h;
            wfragB[g] = f2bf(weight[bb * 1024 + k * 32 + n]);
        }
        if (g < 2048) {                             // afrag: 2048 (1024 per ks)
            int ks = g >> 10, rest = g & 1023;
            int h = rest >> 9, l = (rest >> 3) & 63, j = rest & 7;
            int k = ks * 32 + (l >> 4) * 8 + j, n = (l & 15) + 16 * h;
            afrag[g] = f2bf(A_w[k * 32 + n]);
        }
        if (g < 16 * 32) {                          // aproj: 512
            int t = g >> 5, j = g & 31;
            float acc = A_b[j];
#pragma unroll
            for (int k = 0; k < 32; k++) acc += attn_emb[t * 32 + k] * A_w[(64 + k) * 32 + j];
            aproj[g] = acc;
        }
    } else {                                        // ---- count ----
        const int c = b - 212;
        for (int i = tid; i < NBC; i += 256) lc[i] = 0;
        __syncthreads();
        const int start = c * CHUNK, end = min(start + CHUNK, NE);
        for (int e = start + tid; e < end; e += 256) atomicAdd(&lc[ed[e] >> 6], 1);
        __syncthreads();
        for (int i = tid; i < NBC; i += 256) cpb_t[i * 256 + c] = lc[i];
    }
}

// ---------------------------------------------------------------------------
// K2: scan — one wave per bin (lane = 4 block-counts, shfl_up wave scan),
// then Hillis-Steele over bin totals -> boff[NBC+1].
// ---------------------------------------------------------------------------
__global__ void __launch_bounds__(1024) k_scanB(int* __restrict__ cpb_t,
                                                int* __restrict__ boff) {
    __shared__ int totL[NBC];
    __shared__ int ls[1024];
    const int tid = threadIdx.x, lane = tid & 63, wv = tid >> 6;
    for (int bin = wv; bin < NBC; bin += 16) {
        int4 c = *(int4*)&cpb_t[bin * 256 + lane * 4];
        int lsum = c.x + c.y + c.z + c.w;
        int incl = lsum;
#pragma unroll
        for (int off = 1; off < 64; off <<= 1) {
            int t = __shfl_up(incl, off, 64);
            if (lane >= off) incl += t;
        }
        int excl = incl - lsum;
        int4 o;
        o.x = excl; o.y = excl + c.x; o.z = o.y + c.y; o.w = o.z + c.z;
        *(int4*)&cpb_t[bin * 256 + lane * 4] = o;
        if (lane == 63) totL[bin] = incl;
    }
    __syncthreads();
    int v = (tid < NBC) ? totL[tid] : 0;
    ls[tid] = v;
    __syncthreads();
    for (int off = 1; off < 1024; off <<= 1) {
        int t = (tid >= off) ? ls[tid - off] : 0;
        __syncthreads();
        ls[tid] += t;
        __syncthreads();
    }
    if (tid < NBC) boff[tid] = ls[tid] - v;
    if (tid == 0) boff[NBC] = NE;
}

// ---------------------------------------------------------------------------
// K3: bucket scatter, precomputed cursors, LDS atomics only.
// ebuf[slot] = {src, (type<<16)|dst}  (dst < 65536).
// ---------------------------------------------------------------------------
__global__ void __launch_bounds__(256) k_scatB(const int* __restrict__ es,
                                               const int* __restrict__ ed,
                                               const int* __restrict__ et,
                                               const int* __restrict__ cpb_t,
                                               const int* __restrict__ boff,
                                               int2* __restrict__ ebuf) {
    __shared__ int cur[NBC];
    for (int i = threadIdx.x; i < NBC; i += 256)
        cur[i] = boff[i] + cpb_t[i * 256 + blockIdx.x];
    __syncthreads();
    const int start = blockIdx.x * CHUNK, end = min(start + CHUNK, NE);
    for (int e = start + threadIdx.x; e < end; e += 256) {
        int s = es[e], d = ed[e], t = et[e];
        int slot = atomicAdd(&cur[d >> 6], 1);
        int2 p; p.x = s; p.y = (t << 16) | d;
        ebuf[slot] = p;
    }
}

// ---------------------------------------------------------------------------
// K4: per-tile message kernel (R7-k_msg TLP: one wave per 16-edge tile,
// 50000 tiles, NE%16==0 -> no partial tiles). Basis trick: no type sort.
//   zb[b] = x @ Wb (8 mfma), hid = x@A0 + y@A1 (4 mfma)
//   msg = sum_b w_comp[t,b]*zb[b]  (float4 w_comp row, per C-row)
//   a = sigmoid(relu(hid + aproj[t]) . B_w + B_b)   (16-lane butterfly)
//   amsg[slot] = bf16(a*msg)   -- written at ebuf slot: coalesced, and
//   bucket-contiguous for k_agg.
// ---------------------------------------------------------------------------
__global__ void __launch_bounds__(256) k_msg(
    const int2* __restrict__ ebuf, const unsigned short* __restrict__ wfragB,
    const unsigned short* __restrict__ afrag, const float* __restrict__ aproj,
    const float* __restrict__ w_comp, const float* __restrict__ B_w,
    const float* __restrict__ B_b, const unsigned short* __restrict__ init_bf,
    unsigned short* __restrict__ amsg) {
    const int wave = threadIdx.x >> 6, lane = threadIdx.x & 63;
    const int m = lane & 15, quad = lane >> 4;
    const int tb = (blockIdx.x * 4 + wave) * 16;     // tile base (always full)
    int2 E = ebuf[tb + m];
    int src = E.x, dst = E.y & 0xFFFF;
    short8 xa = *(const short8*)(init_bf + (size_t)src * 32 + quad * 8);
    short8 ya = *(const short8*)(init_bf + (size_t)dst * 32 + quad * 8);
    short8 wb[4][2];
#pragma unroll
    for (int bb = 0; bb < 4; bb++)
#pragma unroll
        for (int h = 0; h < 2; h++)
            wb[bb][h] = *(const short8*)(wfragB + (size_t)((bb * 2 + h) * 64 + lane) * 8);
    short8 a00 = *(const short8*)(afrag + (size_t)(0 * 64 + lane) * 8);
    short8 a01 = *(const short8*)(afrag + (size_t)(1 * 64 + lane) * 8);
    short8 a10 = *(const short8*)(afrag + (size_t)(2 * 64 + lane) * 8);
    short8 a11 = *(const short8*)(afrag + (size_t)(3 * 64 + lane) * 8);
    floatx4 z4 = {0.f, 0.f, 0.f, 0.f};
    floatx4 zb[4][2];
#pragma unroll
    for (int bb = 0; bb < 4; bb++) {
        zb[bb][0] = __builtin_amdgcn_mfma_f32_16x16x32_bf16(xa, wb[bb][0], z4, 0, 0, 0);
        zb[bb][1] = __builtin_amdgcn_mfma_f32_16x16x32_bf16(xa, wb[bb][1], z4, 0, 0, 0);
    }
    floatx4 hc0 = __builtin_amdgcn_mfma_f32_16x16x32_bf16(xa, a00, z4, 0, 0, 0);
    hc0 = __builtin_amdgcn_mfma_f32_16x16x32_bf16(ya, a10, hc0, 0, 0, 0);
    floatx4 hc1 = __builtin_amdgcn_mfma_f32_16x16x32_bf16(xa, a01, z4, 0, 0, 0);
    hc1 = __builtin_amdgcn_mfma_f32_16x16x32_bf16(ya, a11, hc1, 0, 0, 0);
    const float bw0 = B_w[m], bw1 = B_w[m + 16], bb_ = B_b[0];
    int packv = E.y;
#pragma unroll
    for (int r = 0; r < 4; r++) {
        const int srow = quad * 4 + r;
        int tr = __shfl(packv, srow, 64) >> 16;      // type of edge at C-row srow
        float4 wc = ((const float4*)w_comp)[tr];
        float m0 = wc.x * zb[0][0][r] + wc.y * zb[1][0][r] + wc.z * zb[2][0][r] + wc.w * zb[3][0][r];
        float m1 = wc.x * zb[0][1][r] + wc.y * zb[1][1][r] + wc.z * zb[2][1][r] + wc.w * zb[3][1][r];
        float h0 = hc0[r] + aproj[tr * 32 + m];
        float h1 = hc1[r] + aproj[tr * 32 + 16 + m];
        float part = fmaxf(h0, 0.f) * bw0 + fmaxf(h1, 0.f) * bw1;
#pragma unroll
        for (int sft = 1; sft < 16; sft <<= 1) part += __shfl_xor(part, sft, 64);
        float a = 1.f / (1.f + __expf(-(part + bb_)));
        amsg[(size_t)(tb + srow) * 32 + m] = f2bf(a * m0);
        amsg[(size_t)(tb + srow) * 32 + m + 16] = f2bf(a * m1);
    }
}

// ---------------------------------------------------------------------------
// K5: per-bucket aggregation. Block streams its contiguous amsg slice +
// ebuf tags, per-lane ds_add_f32 into accL[64][33] (random rows -> ~2
// lanes/bank, free), then fused self-loop GEMM + ReLU writeback. No serial
// chains (the R8 k_edge lesson), no global atomics.
// ---------------------------------------------------------------------------
__global__ void __launch_bounds__(256) k_agg(
    const int* __restrict__ boff, const int2* __restrict__ ebuf,
    const unsigned short* __restrict__ amsg, const float* __restrict__ S,
    float* __restrict__ out) {
    __shared__ float accL[64 * 33];
    __shared__ float SL[1024];
    const int tid = threadIdx.x, B = blockIdx.x;
    for (int i = tid; i < 1024; i += 256) SL[i] = S[i];
    for (int i = tid; i < 64 * 33; i += 256) accL[i] = 0.f;
    const int s0 = boff[B], s1 = boff[B + 1];
    __syncthreads();

    for (int e = s0 + tid; e < s1; e += 256) {
        int dl = ebuf[e].y & 63;                     // dst & 63 (bucket-local)
        const short8* mp = (const short8*)(amsg + (size_t)e * 32);
        float* ap = &accL[dl * 33];
#pragma unroll
        for (int c = 0; c < 4; c++) {
            short8 mv = mp[c];
#pragma unroll
            for (int j = 0; j < 8; j++)
                atomicAdd(&ap[c * 8 + j], bf2f((unsigned short)mv[j]));
        }
    }
    __syncthreads();

    // writeback: node = tid>>2, 8-col chunk; fused self-loop + relu
    const int node = tid >> 2, c0 = (tid & 3) * 8;
    const int v = B * 64 + node;
    if (v < NN) {
        float acc[8];
#pragma unroll
        for (int j = 0; j < 8; j++) acc[j] = accL[node * 33 + c0 + j];
        float x[32];
        const float4* xp = (const float4*)(out + (size_t)v * 64);
#pragma unroll
        for (int q = 0; q < 8; q++) {
            float4 f = xp[q];
            x[4 * q] = f.x; x[4 * q + 1] = f.y; x[4 * q + 2] = f.z; x[4 * q + 3] = f.w;
        }
#pragma unroll
        for (int d = 0; d < 32; d++) {
            float xd = x[d];
#pragma unroll
            for (int j = 0; j < 8; j++) acc[j] += xd * SL[d * 32 + c0 + j];
        }
        float4* op = (float4*)(out + (size_t)v * 64 + 32 + c0);
#pragma unroll
        for (int q = 0; q < 2; q++) {
            float4 f;
            f.x = fmaxf(acc[4 * q], 0.f);
            f.y = fmaxf(acc[4 * q + 1], 0.f);
            f.z = fmaxf(acc[4 * q + 2], 0.f);
            f.w = fmaxf(acc[4 * q + 3], 0.f);
            op[q] = f;
        }
    }
}

extern "C" void kernel_launch(void* const* d_in, const int* in_sizes, int n_in,
                              void* d_out, int out_size, void* d_ws, size_t ws_size,
                              hipStream_t stream) {
    const float* feat      = (const float*)d_in[0];
    const float* embed     = (const float*)d_in[1];
    const float* transform = (const float*)d_in[2];
    const float* weight    = (const float*)d_in[3];
    const float* w_comp    = (const float*)d_in[4];
    const float* self_w    = (const float*)d_in[5];
    const float* A_w       = (const float*)d_in[6];
    const float* A_b       = (const float*)d_in[7];
    const float* B_w       = (const float*)d_in[8];
    const float* B_b       = (const float*)d_in[9];
    const float* attn_emb  = (const float*)d_in[10];
    const int*   idx       = (const int*)d_in[11];
    const int*   edge_src  = (const int*)d_in[12];
    const int*   edge_dst  = (const int*)d_in[13];
    const int*   edge_type = (const int*)d_in[14];
    float* out = (float*)d_out;

    // -------- workspace layout (~61.6 MB; poison fill is full-ws_size and
    // constant regardless, so layout size is not a cost knob) --------
    char* ws = (char*)d_ws;
    int2*           ebuf    = (int2*)ws;                               // 6,400,000 B
    unsigned short* init_bf = (unsigned short*)(ws + (size_t)NE * 8);  // 3,200,000 B
    unsigned short* wfragB  = (unsigned short*)((char*)init_bf + 3200000);  // 8,192 B
    unsigned short* afrag   = (unsigned short*)((char*)wfragB + 8192);      // 4,096 B
    float*          aproj   = (float*)((char*)afrag + 4096);                // 2,048 B
    int*            cpb_t   = (int*)((char*)aproj + 2048);             // 800,768 B
    int*            boff    = cpb_t + NBC * 256;                       // 3,132 B
    unsigned short* amsg    = (unsigned short*)((char*)(boff + NBC + 2)); // NE*64 B

    k_phase1<<<212 + ABLK, 256, 0, stream>>>(feat, embed, transform, idx, weight,
                                             A_w, A_b, attn_emb, edge_dst,
                                             out, init_bf, wfragB, afrag, aproj, cpb_t);
    k_scanB<<<1, 1024, 0, stream>>>(cpb_t, boff);
    k_scatB<<<ABLK, 256, 0, stream>>>(edge_src, edge_dst, edge_type, cpb_t, boff, ebuf);
    k_msg<<<NE / 64, 256, 0, stream>>>(ebuf, wfragB, afrag, aproj, w_comp,
                                       B_w, B_b, init_bf, amsg);
    k_agg<<<NBC, 256, 0, stream>>>(boff, ebuf, amsg, self_w, out);
}

// Round 10
// 226.360 us; speedup vs baseline: 1.6341x; 1.6341x over previous
//
#include <hip/hip_runtime.h>
#include <math.h>

#define NN 50000
#define NE 800000
#define NR 16
#define NBC 782                          // dst buckets of 64 nodes: ceil(50000/64)
#define ABLK 256                         // blocks in count/scatter passes
#define CHUNK ((NE + ABLK - 1) / ABLK)   // 3125

typedef __attribute__((ext_vector_type(8))) short short8;
typedef __attribute__((ext_vector_type(4))) float floatx4;

__device__ __forceinline__ unsigned short f2bf(float x) {
    unsigned int u = __float_as_uint(x);
    u += 0x7fffu + ((u >> 16) & 1u);
    return (unsigned short)(u >> 16);
}
__device__ __forceinline__ float bf2f(unsigned short s) {
    return __uint_as_float(((unsigned int)s) << 16);
}

// ---------------------------------------------------------------------------
// K1 (fused): blocks [0,196) init | [196,212) frag prep | [212,468) count.
// ---------------------------------------------------------------------------
__global__ void __launch_bounds__(256) k_phase1(
    const float* __restrict__ feat, const float* __restrict__ emb,
    const float* __restrict__ T, const int* __restrict__ idx,
    const float* __restrict__ weight, const float* __restrict__ A_w,
    const float* __restrict__ A_b, const float* __restrict__ attn_emb,
    const int* __restrict__ ed,
    float* __restrict__ out, unsigned short* __restrict__ init_bf,
    unsigned short* __restrict__ wfragB, unsigned short* __restrict__ afrag,
    float* __restrict__ aproj, int* __restrict__ cpb_t) {
    __shared__ int lc[NBC];
    const int b = blockIdx.x, tid = threadIdx.x;
    if (b < 196) {                                  // ---- init ----
        int i = b * 256 + tid;
        if (i >= NN) return;
        float v[32], acc[32];
#pragma unroll
        for (int o = 0; o < 32; o++) acc[o] = 0.f;
        const float4* fp = (const float4*)(feat + (size_t)i * 32);
#pragma unroll
        for (int q = 0; q < 8; q++) {
            float4 f = fp[q];
            v[4 * q] = f.x; v[4 * q + 1] = f.y; v[4 * q + 2] = f.z; v[4 * q + 3] = f.w;
        }
#pragma unroll
        for (int d = 0; d < 32; d++) {
            float xd = v[d];
#pragma unroll
            for (int o = 0; o < 32; o++) acc[o] += xd * T[d * 32 + o];
        }
        int row = idx[i];
        const float4* ep = (const float4*)(emb + (size_t)row * 32);
#pragma unroll
        for (int q = 0; q < 8; q++) {
            float4 f = ep[q];
            v[4 * q] = f.x; v[4 * q + 1] = f.y; v[4 * q + 2] = f.z; v[4 * q + 3] = f.w;
        }
#pragma unroll
        for (int d = 0; d < 32; d++) {
            float xd = v[d];
#pragma unroll
            for (int o = 0; o < 32; o++) acc[o] += xd * T[(32 + d) * 32 + o];
        }
        float4* op = (float4*)(out + (size_t)i * 64);
#pragma unroll
        for (int q = 0; q < 8; q++) {
            float4 f;
            f.x = acc[4 * q]; f.y = acc[4 * q + 1]; f.z = acc[4 * q + 2]; f.w = acc[4 * q + 3];
            op[q] = f;
        }
        unsigned int w[16];
#pragma unroll
        for (int q = 0; q < 16; q++)
            w[q] = (unsigned int)f2bf(acc[2 * q]) | ((unsigned int)f2bf(acc[2 * q + 1]) << 16);
        uint4* bp = (uint4*)(init_bf + (size_t)i * 32);
#pragma unroll
        for (int q = 0; q < 4; q++) {
            uint4 u; u.x = w[4 * q]; u.y = w[4 * q + 1]; u.z = w[4 * q + 2]; u.w = w[4 * q + 3];
            bp[q] = u;
        }
    } else if (b < 212) {                           // ---- prep ----
        int g = (b - 196) * 256 + tid;
        if (g < 4 * 1024) {                         // wfragB: 4096 (1024/basis)
            int bb = g >> 10, rest = g & 1023;
            int h = rest >> 9, l = (rest >> 3) & 63, j = rest & 7;
            int k = (l >> 4) * 8 + j, n = (l & 15) + 16 * h;
            wfragB[g] = f2bf(weight[bb * 1024 + k * 32 + n]);
        }
        if (g < 2048) {                             // afrag: 2048 (1024 per ks)
            int ks = g >> 10, rest = g & 1023;
            int h = rest >> 9, l = (rest >> 3) & 63, j = rest & 7;
            int k = ks * 32 + (l >> 4) * 8 + j, n = (l & 15) + 16 * h;
            afrag[g] = f2bf(A_w[k * 32 + n]);
        }
        if (g < 16 * 32) {                          // aproj: 512
            int t = g >> 5, j = g & 31;
            float acc = A_b[j];
#pragma unroll
            for (int k = 0; k < 32; k++) acc += attn_emb[t * 32 + k] * A_w[(64 + k) * 32 + j];
            aproj[g] = acc;
        }
    } else {                                        // ---- count ----
        const int c = b - 212;
        for (int i = tid; i < NBC; i += 256) lc[i] = 0;
        __syncthreads();
        const int start = c * CHUNK, end = min(start + CHUNK, NE);
        for (int e = start + tid; e < end; e += 256) atomicAdd(&lc[ed[e] >> 6], 1);
        __syncthreads();
        for (int i = tid; i < NBC; i += 256) cpb_t[i * 256 + c] = lc[i];
    }
}

// ---------------------------------------------------------------------------
// K2: scan — one wave per bin, then Hillis-Steele over bin totals -> boff.
// ---------------------------------------------------------------------------
__global__ void __launch_bounds__(1024) k_scanB(int* __restrict__ cpb_t,
                                                int* __restrict__ boff) {
    __shared__ int totL[NBC];
    __shared__ int ls[1024];
    const int tid = threadIdx.x, lane = tid & 63, wv = tid >> 6;
    for (int bin = wv; bin < NBC; bin += 16) {
        int4 c = *(int4*)&cpb_t[bin * 256 + lane * 4];
        int lsum = c.x + c.y + c.z + c.w;
        int incl = lsum;
#pragma unroll
        for (int off = 1; off < 64; off <<= 1) {
            int t = __shfl_up(incl, off, 64);
            if (lane >= off) incl += t;
        }
        int excl = incl - lsum;
        int4 o;
        o.x = excl; o.y = excl + c.x; o.z = o.y + c.y; o.w = o.z + c.z;
        *(int4*)&cpb_t[bin * 256 + lane * 4] = o;
        if (lane == 63) totL[bin] = incl;
    }
    __syncthreads();
    int v = (tid < NBC) ? totL[tid] : 0;
    ls[tid] = v;
    __syncthreads();
    for (int off = 1; off < 1024; off <<= 1) {
        int t = (tid >= off) ? ls[tid - off] : 0;
        __syncthreads();
        ls[tid] += t;
        __syncthreads();
    }
    if (tid < NBC) boff[tid] = ls[tid] - v;
    if (tid == 0) boff[NBC] = NE;
}

// ---------------------------------------------------------------------------
// K3: bucket scatter, precomputed cursors, native int LDS atomics only.
// ebuf[slot] = {src, (type<<16)|dst}.
// ---------------------------------------------------------------------------
__global__ void __launch_bounds__(256) k_scatB(const int* __restrict__ es,
                                               const int* __restrict__ ed,
                                               const int* __restrict__ et,
                                               const int* __restrict__ cpb_t,
                                               const int* __restrict__ boff,
                                               int2* __restrict__ ebuf) {
    __shared__ int cur[NBC];
    for (int i = threadIdx.x; i < NBC; i += 256)
        cur[i] = boff[i] + cpb_t[i * 256 + blockIdx.x];
    __syncthreads();
    const int start = blockIdx.x * CHUNK, end = min(start + CHUNK, NE);
    for (int e = start + threadIdx.x; e < end; e += 256) {
        int s = es[e], d = ed[e], t = et[e];
        int slot = atomicAdd(&cur[d >> 6], 1);
        int2 p; p.x = s; p.y = (t << 16) | d;
        ebuf[slot] = p;
    }
}

// ---------------------------------------------------------------------------
// K4: within-bucket dst sort (R9 lesson: float LDS atomicAdd in the
// aggregator was a 176us CAS/serialization trap — sort with NATIVE INT LDS
// atomics instead, then aggregate with zero atomics).
// One block per 64-node bucket: 64-bin hist -> wave scan -> row_off CSR +
// reorder ebuf -> ebuf2 (dst-sorted).
// ---------------------------------------------------------------------------
__global__ void __launch_bounds__(256) k_fine(const int* __restrict__ boff,
                                              const int2* __restrict__ ebuf,
                                              int2* __restrict__ ebuf2,
                                              int* __restrict__ row_off) {
    __shared__ int h[64], cur[64];
    const int B = blockIdx.x, tid = threadIdx.x;
    const int s0 = boff[B], s1 = boff[B + 1];
    if (tid < 64) h[tid] = 0;
    __syncthreads();
    for (int e = s0 + tid; e < s1; e += 256)
        atomicAdd(&h[ebuf[e].y & 63], 1);
    __syncthreads();
    if (tid < 64) {
        int v = h[tid];
        int incl = v;
#pragma unroll
        for (int off = 1; off < 64; off <<= 1) {
            int t = __shfl_up(incl, off, 64);
            if (tid >= off) incl += t;
        }
        int base = s0 + incl - v;        // exclusive
        cur[tid] = base;
        row_off[B * 64 + tid] = base;    // row_off[NN]=NE covered by last bucket
    }
    __syncthreads();
    for (int e = s0 + tid; e < s1; e += 256) {
        int2 E = ebuf[e];
        int p = atomicAdd(&cur[E.y & 63], 1);
        ebuf2[p] = E;
    }
}

// ---------------------------------------------------------------------------
// K5: per-tile message kernel (one wave per 16-edge tile, 50000 tiles).
// Reads dst-SORTED ebuf2 -> amsg[e] coalesced writes are automatically in
// CSR order for k_agg. Basis trick: msg = sum_b w_comp[t,b]*(x@Wb).
// ---------------------------------------------------------------------------
__global__ void __launch_bounds__(256) k_msg(
    const int2* __restrict__ ebuf2, const unsigned short* __restrict__ wfragB,
    const unsigned short* __restrict__ afrag, const float* __restrict__ aproj,
    const float* __restrict__ w_comp, const float* __restrict__ B_w,
    const float* __restrict__ B_b, const unsigned short* __restrict__ init_bf,
    unsigned short* __restrict__ amsg) {
    const int wave = threadIdx.x >> 6, lane = threadIdx.x & 63;
    const int m = lane & 15, quad = lane >> 4;
    const int tb = (blockIdx.x * 4 + wave) * 16;     // tile base (always full)
    int2 E = ebuf2[tb + m];
    int src = E.x, dst = E.y & 0xFFFF;
    short8 xa = *(const short8*)(init_bf + (size_t)src * 32 + quad * 8);
    short8 ya = *(const short8*)(init_bf + (size_t)dst * 32 + quad * 8);
    short8 wb[4][2];
#pragma unroll
    for (int bb = 0; bb < 4; bb++)
#pragma unroll
        for (int h = 0; h < 2; h++)
            wb[bb][h] = *(const short8*)(wfragB + (size_t)((bb * 2 + h) * 64 + lane) * 8);
    short8 a00 = *(const short8*)(afrag + (size_t)(0 * 64 + lane) * 8);
    short8 a01 = *(const short8*)(afrag + (size_t)(1 * 64 + lane) * 8);
    short8 a10 = *(const short8*)(afrag + (size_t)(2 * 64 + lane) * 8);
    short8 a11 = *(const short8*)(afrag + (size_t)(3 * 64 + lane) * 8);
    floatx4 z4 = {0.f, 0.f, 0.f, 0.f};
    floatx4 zb[4][2];
#pragma unroll
    for (int bb = 0; bb < 4; bb++) {
        zb[bb][0] = __builtin_amdgcn_mfma_f32_16x16x32_bf16(xa, wb[bb][0], z4, 0, 0, 0);
        zb[bb][1] = __builtin_amdgcn_mfma_f32_16x16x32_bf16(xa, wb[bb][1], z4, 0, 0, 0);
    }
    floatx4 hc0 = __builtin_amdgcn_mfma_f32_16x16x32_bf16(xa, a00, z4, 0, 0, 0);
    hc0 = __builtin_amdgcn_mfma_f32_16x16x32_bf16(ya, a10, hc0, 0, 0, 0);
    floatx4 hc1 = __builtin_amdgcn_mfma_f32_16x16x32_bf16(xa, a01, z4, 0, 0, 0);
    hc1 = __builtin_amdgcn_mfma_f32_16x16x32_bf16(ya, a11, hc1, 0, 0, 0);
    const float bw0 = B_w[m], bw1 = B_w[m + 16], bb_ = B_b[0];
    int packv = E.y;
#pragma unroll
    for (int r = 0; r < 4; r++) {
        const int srow = quad * 4 + r;
        int tr = __shfl(packv, srow, 64) >> 16;      // type of edge at C-row srow
        float4 wc = ((const float4*)w_comp)[tr];
        float m0 = wc.x * zb[0][0][r] + wc.y * zb[1][0][r] + wc.z * zb[2][0][r] + wc.w * zb[3][0][r];
        float m1 = wc.x * zb[0][1][r] + wc.y * zb[1][1][r] + wc.z * zb[2][1][r] + wc.w * zb[3][1][r];
        float h0 = hc0[r] + aproj[tr * 32 + m];
        float h1 = hc1[r] + aproj[tr * 32 + 16 + m];
        float part = fmaxf(h0, 0.f) * bw0 + fmaxf(h1, 0.f) * bw1;
#pragma unroll
        for (int sft = 1; sft < 16; sft <<= 1) part += __shfl_xor(part, sft, 64);
        float a = 1.f / (1.f + __expf(-(part + bb_)));
        amsg[(size_t)(tb + srow) * 32 + m] = f2bf(a * m0);
        amsg[(size_t)(tb + srow) * 32 + m + 16] = f2bf(a * m1);
    }
}

// ---------------------------------------------------------------------------
// K6: CSR streaming aggregation (R7-proven) — ZERO atomics. 4 threads per
// node (8 cols each); node's amsg rows are contiguous. Fused self-loop
// GEMM + ReLU.
// ---------------------------------------------------------------------------
__global__ void __launch_bounds__(256) k_agg(
    const int* __restrict__ row_off, const unsigned short* __restrict__ amsg,
    const float* __restrict__ S, float* __restrict__ out) {
    int tid = threadIdx.x;
    int v = blockIdx.x * 64 + (tid >> 2);
    if (v >= NN) return;
    int c0 = (tid & 3) * 8;
    float acc[8];
#pragma unroll
    for (int j = 0; j < 8; j++) acc[j] = 0.f;
    int p0 = row_off[v], p1 = row_off[v + 1];
    for (int p = p0; p < p1; p++) {
        short8 mv = *(const short8*)(amsg + (size_t)p * 32 + c0);
#pragma unroll
        for (int j = 0; j < 8; j++) acc[j] += bf2f((unsigned short)mv[j]);
    }
    float x[32];
    const float4* xp = (const float4*)(out + (size_t)v * 64);
#pragma unroll
    for (int q = 0; q < 8; q++) {
        float4 f = xp[q];
        x[4 * q] = f.x; x[4 * q + 1] = f.y; x[4 * q + 2] = f.z; x[4 * q + 3] = f.w;
    }
#pragma unroll
    for (int d = 0; d < 32; d++) {
        float xd = x[d];
#pragma unroll
        for (int j = 0; j < 8; j++) acc[j] += xd * S[d * 32 + c0 + j];
    }
    float4* op = (float4*)(out + (size_t)v * 64 + 32 + c0);
#pragma unroll
    for (int q = 0; q < 2; q++) {
        float4 f;
        f.x = fmaxf(acc[4 * q], 0.f);
        f.y = fmaxf(acc[4 * q + 1], 0.f);
        f.z = fmaxf(acc[4 * q + 2], 0.f);
        f.w = fmaxf(acc[4 * q + 3], 0.f);
        op[q] = f;
    }
}

extern "C" void kernel_launch(void* const* d_in, const int* in_sizes, int n_in,
                              void* d_out, int out_size, void* d_ws, size_t ws_size,
                              hipStream_t stream) {
    const float* feat      = (const float*)d_in[0];
    const float* embed     = (const float*)d_in[1];
    const float* transform = (const float*)d_in[2];
    const float* weight    = (const float*)d_in[3];
    const float* w_comp    = (const float*)d_in[4];
    const float* self_w    = (const float*)d_in[5];
    const float* A_w       = (const float*)d_in[6];
    const float* A_b       = (const float*)d_in[7];
    const float* B_w       = (const float*)d_in[8];
    const float* B_b       = (const float*)d_in[9];
    const float* attn_emb  = (const float*)d_in[10];
    const int*   idx       = (const int*)d_in[11];
    const int*   edge_src  = (const int*)d_in[12];
    const int*   edge_dst  = (const int*)d_in[13];
    const int*   edge_type = (const int*)d_in[14];
    float* out = (float*)d_out;

    // -------- workspace layout (~72 MB of 256 MiB; fill cost is constant) ----
    char* ws = (char*)d_ws;
    int2*           ebuf    = (int2*)ws;                                    // 6.4 MB
    int2*           ebuf2   = (int2*)(ws + (size_t)NE * 8);                 // 6.4 MB
    unsigned short* init_bf = (unsigned short*)(ws + (size_t)NE * 16);      // 3.2 MB
    unsigned short* wfragB  = (unsigned short*)((char*)init_bf + 3200000);  // 8 KB
    unsigned short* afrag   = (unsigned short*)((char*)wfragB + 8192);      // 4 KB
    float*          aproj   = (float*)((char*)afrag + 4096);                // 2 KB
    int*            cpb_t   = (int*)((char*)aproj + 2048);                  // 800 KB
    int*            boff    = cpb_t + NBC * 256;                            // NBC+1
    int*            row_off = boff + NBC + 1;                               // NBC*64+1
    unsigned short* amsg    = (unsigned short*)(row_off + NBC * 64 + 64);   // 51.2 MB

    k_phase1<<<212 + ABLK, 256, 0, stream>>>(feat, embed, transform, idx, weight,
                                             A_w, A_b, attn_emb, edge_dst,
                                             out, init_bf, wfragB, afrag, aproj, cpb_t);
    k_scanB<<<1, 1024, 0, stream>>>(cpb_t, boff);
    k_scatB<<<ABLK, 256, 0, stream>>>(edge_src, edge_dst, edge_type, cpb_t, boff, ebuf);
    k_fine<<<NBC, 256, 0, stream>>>(boff, ebuf, ebuf2, row_off);
    k_msg<<<NE / 64, 256, 0, stream>>>(ebuf2, wfragB, afrag, aproj, w_comp,
                                       B_w, B_b, init_bf, amsg);
    k_agg<<<NBC, 256, 0, stream>>>(row_off, amsg, self_w, out);
}

// Round 11
// 223.205 us; speedup vs baseline: 1.6572x; 1.0141x over previous
//
#include <hip/hip_runtime.h>
#include <math.h>

#define NN 50000
#define NE 800000
#define NR 16
#define NBC 782                          // dst buckets of 64 nodes: ceil(50000/64)
#define ABLK 256                         // blocks in count/scatter passes
#define CHUNK ((NE + ABLK - 1) / ABLK)   // 3125

typedef __attribute__((ext_vector_type(8))) short short8;
typedef __attribute__((ext_vector_type(4))) float floatx4;

__device__ __forceinline__ unsigned short f2bf(float x) {
    unsigned int u = __float_as_uint(x);
    u += 0x7fffu + ((u >> 16) & 1u);
    return (unsigned short)(u >> 16);
}
__device__ __forceinline__ float bf2f(unsigned short s) {
    return __uint_as_float(((unsigned int)s) << 16);
}

// ---------------------------------------------------------------------------
// K1 (fused): blocks [0,196) init | [196,212) frag prep | [212,468) count.
// ---------------------------------------------------------------------------
__global__ void __launch_bounds__(256) k_phase1(
    const float* __restrict__ feat, const float* __restrict__ emb,
    const float* __restrict__ T, const int* __restrict__ idx,
    const float* __restrict__ weight, const float* __restrict__ A_w,
    const float* __restrict__ A_b, const float* __restrict__ attn_emb,
    const int* __restrict__ ed,
    float* __restrict__ out, unsigned short* __restrict__ init_bf,
    unsigned short* __restrict__ wfragB, unsigned short* __restrict__ afrag,
    float* __restrict__ aproj, int* __restrict__ cpb_t) {
    __shared__ int lc[NBC];
    const int b = blockIdx.x, tid = threadIdx.x;
    if (b < 196) {                                  // ---- init ----
        int i = b * 256 + tid;
        if (i >= NN) return;
        float v[32], acc[32];
#pragma unroll
        for (int o = 0; o < 32; o++) acc[o] = 0.f;
        const float4* fp = (const float4*)(feat + (size_t)i * 32);
#pragma unroll
        for (int q = 0; q < 8; q++) {
            float4 f = fp[q];
            v[4 * q] = f.x; v[4 * q + 1] = f.y; v[4 * q + 2] = f.z; v[4 * q + 3] = f.w;
        }
#pragma unroll
        for (int d = 0; d < 32; d++) {
            float xd = v[d];
#pragma unroll
            for (int o = 0; o < 32; o++) acc[o] += xd * T[d * 32 + o];
        }
        int row = idx[i];
        const float4* ep = (const float4*)(emb + (size_t)row * 32);
#pragma unroll
        for (int q = 0; q < 8; q++) {
            float4 f = ep[q];
            v[4 * q] = f.x; v[4 * q + 1] = f.y; v[4 * q + 2] = f.z; v[4 * q + 3] = f.w;
        }
#pragma unroll
        for (int d = 0; d < 32; d++) {
            float xd = v[d];
#pragma unroll
            for (int o = 0; o < 32; o++) acc[o] += xd * T[(32 + d) * 32 + o];
        }
        float4* op = (float4*)(out + (size_t)i * 64);
#pragma unroll
        for (int q = 0; q < 8; q++) {
            float4 f;
            f.x = acc[4 * q]; f.y = acc[4 * q + 1]; f.z = acc[4 * q + 2]; f.w = acc[4 * q + 3];
            op[q] = f;
        }
        unsigned int w[16];
#pragma unroll
        for (int q = 0; q < 16; q++)
            w[q] = (unsigned int)f2bf(acc[2 * q]) | ((unsigned int)f2bf(acc[2 * q + 1]) << 16);
        uint4* bp = (uint4*)(init_bf + (size_t)i * 32);
#pragma unroll
        for (int q = 0; q < 4; q++) {
            uint4 u; u.x = w[4 * q]; u.y = w[4 * q + 1]; u.z = w[4 * q + 2]; u.w = w[4 * q + 3];
            bp[q] = u;
        }
    } else if (b < 212) {                           // ---- prep ----
        int g = (b - 196) * 256 + tid;
        if (g < 4 * 1024) {                         // wfragB: 4096 (1024/basis)
            int bb = g >> 10, rest = g & 1023;
            int h = rest >> 9, l = (rest >> 3) & 63, j = rest & 7;
            int k = (l >> 4) * 8 + j, n = (l & 15) + 16 * h;
            wfragB[g] = f2bf(weight[bb * 1024 + k * 32 + n]);
        }
        if (g < 2048) {                             // afrag: 2048 (1024 per ks)
            int ks = g >> 10, rest = g & 1023;
            int h = rest >> 9, l = (rest >> 3) & 63, j = rest & 7;
            int k = ks * 32 + (l >> 4) * 8 + j, n = (l & 15) + 16 * h;
            afrag[g] = f2bf(A_w[k * 32 + n]);
        }
        if (g < 16 * 32) {                          // aproj: 512
            int t = g >> 5, j = g & 31;
            float acc = A_b[j];
#pragma unroll
            for (int k = 0; k < 32; k++) acc += attn_emb[t * 32 + k] * A_w[(64 + k) * 32 + j];
            aproj[g] = acc;
        }
    } else {                                        // ---- count ----
        const int c = b - 212;
        for (int i = tid; i < NBC; i += 256) lc[i] = 0;
        __syncthreads();
        const int start = c * CHUNK, end = min(start + CHUNK, NE);
        for (int e = start + tid; e < end; e += 256) atomicAdd(&lc[ed[e] >> 6], 1);
        __syncthreads();
        for (int i = tid; i < NBC; i += 256) cpb_t[i * 256 + c] = lc[i];
    }
}

// ---------------------------------------------------------------------------
// K2: scan — one wave per bin, then Hillis-Steele over bin totals -> boff.
// ---------------------------------------------------------------------------
__global__ void __launch_bounds__(1024) k_scanB(int* __restrict__ cpb_t,
                                                int* __restrict__ boff) {
    __shared__ int totL[NBC];
    __shared__ int ls[1024];
    const int tid = threadIdx.x, lane = tid & 63, wv = tid >> 6;
    for (int bin = wv; bin < NBC; bin += 16) {
        int4 c = *(int4*)&cpb_t[bin * 256 + lane * 4];
        int lsum = c.x + c.y + c.z + c.w;
        int incl = lsum;
#pragma unroll
        for (int off = 1; off < 64; off <<= 1) {
            int t = __shfl_up(incl, off, 64);
            if (lane >= off) incl += t;
        }
        int excl = incl - lsum;
        int4 o;
        o.x = excl; o.y = excl + c.x; o.z = o.y + c.y; o.w = o.z + c.z;
        *(int4*)&cpb_t[bin * 256 + lane * 4] = o;
        if (lane == 63) totL[bin] = incl;
    }
    __syncthreads();
    int v = (tid < NBC) ? totL[tid] : 0;
    ls[tid] = v;
    __syncthreads();
    for (int off = 1; off < 1024; off <<= 1) {
        int t = (tid >= off) ? ls[tid - off] : 0;
        __syncthreads();
        ls[tid] += t;
        __syncthreads();
    }
    if (tid < NBC) boff[tid] = ls[tid] - v;
    if (tid == 0) boff[NBC] = NE;
}

// ---------------------------------------------------------------------------
// K3: bucket scatter, precomputed cursors, native int LDS atomics only.
// ebuf[slot] = {src, (type<<16)|dst}.
// ---------------------------------------------------------------------------
__global__ void __launch_bounds__(256) k_scatB(const int* __restrict__ es,
                                               const int* __restrict__ ed,
                                               const int* __restrict__ et,
                                               const int* __restrict__ cpb_t,
                                               const int* __restrict__ boff,
                                               int2* __restrict__ ebuf) {
    __shared__ int cur[NBC];
    for (int i = threadIdx.x; i < NBC; i += 256)
        cur[i] = boff[i] + cpb_t[i * 256 + blockIdx.x];
    __syncthreads();
    const int start = blockIdx.x * CHUNK, end = min(start + CHUNK, NE);
    for (int e = start + threadIdx.x; e < end; e += 256) {
        int s = es[e], d = ed[e], t = et[e];
        int slot = atomicAdd(&cur[d >> 6], 1);
        int2 p; p.x = s; p.y = (t << 16) | d;
        ebuf[slot] = p;
    }
}

// ---------------------------------------------------------------------------
// K4: within-bucket dst sort (native int LDS atomics) -> ebuf2 + row_off CSR.
// ---------------------------------------------------------------------------
__global__ void __launch_bounds__(256) k_fine(const int* __restrict__ boff,
                                              const int2* __restrict__ ebuf,
                                              int2* __restrict__ ebuf2,
                                              int* __restrict__ row_off) {
    __shared__ int h[64], cur[64];
    const int B = blockIdx.x, tid = threadIdx.x;
    const int s0 = boff[B], s1 = boff[B + 1];
    if (tid < 64) h[tid] = 0;
    __syncthreads();
    for (int e = s0 + tid; e < s1; e += 256)
        atomicAdd(&h[ebuf[e].y & 63], 1);
    __syncthreads();
    if (tid < 64) {
        int v = h[tid];
        int incl = v;
#pragma unroll
        for (int off = 1; off < 64; off <<= 1) {
            int t = __shfl_up(incl, off, 64);
            if (tid >= off) incl += t;
        }
        int base = s0 + incl - v;        // exclusive
        cur[tid] = base;
        row_off[B * 64 + tid] = base;    // row_off[NN]=NE covered by last bucket
    }
    __syncthreads();
    for (int e = s0 + tid; e < s1; e += 256) {
        int2 E = ebuf[e];
        int p = atomicAdd(&cur[E.y & 63], 1);
        ebuf2[p] = E;
    }
}

// ---------------------------------------------------------------------------
// K5: per-tile message kernel — R11: TWO tiles per wave (ILP; the weight
// fragments are tile-invariant so only x/y/acc duplicate) + PACKED bf16
// stores (uint = bf16(col m) | bf16(col m+16)<<16 -> one coalesced 4B store
// per row instead of two scattered 2B stores).
// amsg row layout (64 B): 16 uints; uint m holds cols (m, m+16).
// ---------------------------------------------------------------------------
__global__ void __launch_bounds__(256) k_msg(
    const int2* __restrict__ ebuf2, const unsigned short* __restrict__ wfragB,
    const unsigned short* __restrict__ afrag, const float* __restrict__ aproj,
    const float* __restrict__ w_comp, const float* __restrict__ B_w,
    const float* __restrict__ B_b, const unsigned short* __restrict__ init_bf,
    unsigned int* __restrict__ amsg) {
    const int wave = threadIdx.x >> 6, lane = threadIdx.x & 63;
    const int m = lane & 15, quad = lane >> 4;
    const int tb0 = (blockIdx.x * 4 + wave) * 32;    // 2 full tiles (NE%32==0)

    short8 wb[4][2];
#pragma unroll
    for (int bb = 0; bb < 4; bb++)
#pragma unroll
        for (int h = 0; h < 2; h++)
            wb[bb][h] = *(const short8*)(wfragB + (size_t)((bb * 2 + h) * 64 + lane) * 8);
    short8 a00 = *(const short8*)(afrag + (size_t)(0 * 64 + lane) * 8);
    short8 a01 = *(const short8*)(afrag + (size_t)(1 * 64 + lane) * 8);
    short8 a10 = *(const short8*)(afrag + (size_t)(2 * 64 + lane) * 8);
    short8 a11 = *(const short8*)(afrag + (size_t)(3 * 64 + lane) * 8);
    const float bw0 = B_w[m], bw1 = B_w[m + 16], bb_ = B_b[0];
    const floatx4 z4 = {0.f, 0.f, 0.f, 0.f};

#pragma unroll
    for (int t2 = 0; t2 < 2; t2++) {
        const int tb = tb0 + t2 * 16;
        int2 E = ebuf2[tb + m];
        int src = E.x, dst = E.y & 0xFFFF;
        short8 xa = *(const short8*)(init_bf + (size_t)src * 32 + quad * 8);
        short8 ya = *(const short8*)(init_bf + (size_t)dst * 32 + quad * 8);
        floatx4 zb[4][2];
#pragma unroll
        for (int bb = 0; bb < 4; bb++) {
            zb[bb][0] = __builtin_amdgcn_mfma_f32_16x16x32_bf16(xa, wb[bb][0], z4, 0, 0, 0);
            zb[bb][1] = __builtin_amdgcn_mfma_f32_16x16x32_bf16(xa, wb[bb][1], z4, 0, 0, 0);
        }
        floatx4 hc0 = __builtin_amdgcn_mfma_f32_16x16x32_bf16(xa, a00, z4, 0, 0, 0);
        hc0 = __builtin_amdgcn_mfma_f32_16x16x32_bf16(ya, a10, hc0, 0, 0, 0);
        floatx4 hc1 = __builtin_amdgcn_mfma_f32_16x16x32_bf16(xa, a01, z4, 0, 0, 0);
        hc1 = __builtin_amdgcn_mfma_f32_16x16x32_bf16(ya, a11, hc1, 0, 0, 0);
        int packv = E.y;
#pragma unroll
        for (int r = 0; r < 4; r++) {
            const int srow = quad * 4 + r;
            int tr = __shfl(packv, srow, 64) >> 16;  // type of edge at C-row srow
            float4 wc = ((const float4*)w_comp)[tr];
            float m0 = wc.x * zb[0][0][r] + wc.y * zb[1][0][r] + wc.z * zb[2][0][r] + wc.w * zb[3][0][r];
            float m1 = wc.x * zb[0][1][r] + wc.y * zb[1][1][r] + wc.z * zb[2][1][r] + wc.w * zb[3][1][r];
            float h0 = hc0[r] + aproj[tr * 32 + m];
            float h1 = hc1[r] + aproj[tr * 32 + 16 + m];
            float part = fmaxf(h0, 0.f) * bw0 + fmaxf(h1, 0.f) * bw1;
#pragma unroll
            for (int sft = 1; sft < 16; sft <<= 1) part += __shfl_xor(part, sft, 64);
            float a = 1.f / (1.f + __expf(-(part + bb_)));
            unsigned int pkd = (unsigned int)f2bf(a * m0) |
                               ((unsigned int)f2bf(a * m1) << 16);
            amsg[(size_t)(tb + srow) * 16 + m] = pkd;   // quad's 16 lanes: 64 B
        }
    }
}

// ---------------------------------------------------------------------------
// K6: CSR streaming aggregation — ZERO atomics. 4 threads/node; thread k
// reads uints 4k..4k+3 of each contiguous amsg row -> cols {4k..4k+3} (lo)
// and {4k+16..4k+19} (hi). Fused self-loop GEMM + ReLU.
// ---------------------------------------------------------------------------
__global__ void __launch_bounds__(256) k_agg(
    const int* __restrict__ row_off, const unsigned int* __restrict__ amsg,
    const float* __restrict__ S, float* __restrict__ out) {
    int tid = threadIdx.x;
    int v = blockIdx.x * 64 + (tid >> 2);
    if (v >= NN) return;
    int c0 = (tid & 3) * 4;                          // lo cols c0..c0+3, hi +16
    float alo[4], ahi[4];
#pragma unroll
    for (int j = 0; j < 4; j++) { alo[j] = 0.f; ahi[j] = 0.f; }
    int p0 = row_off[v], p1 = row_off[v + 1];
    for (int p = p0; p < p1; p++) {
        uint4 u = *(const uint4*)(amsg + (size_t)p * 16 + c0);
        alo[0] += bf2f((unsigned short)(u.x & 0xFFFF));
        ahi[0] += bf2f((unsigned short)(u.x >> 16));
        alo[1] += bf2f((unsigned short)(u.y & 0xFFFF));
        ahi[1] += bf2f((unsigned short)(u.y >> 16));
        alo[2] += bf2f((unsigned short)(u.z & 0xFFFF));
        ahi[2] += bf2f((unsigned short)(u.z >> 16));
        alo[3] += bf2f((unsigned short)(u.w & 0xFFFF));
        ahi[3] += bf2f((unsigned short)(u.w >> 16));
    }
    float x[32];
    const float4* xp = (const float4*)(out + (size_t)v * 64);
#pragma unroll
    for (int q = 0; q < 8; q++) {
        float4 f = xp[q];
        x[4 * q] = f.x; x[4 * q + 1] = f.y; x[4 * q + 2] = f.z; x[4 * q + 3] = f.w;
    }
#pragma unroll
    for (int d = 0; d < 32; d++) {
        float xd = x[d];
#pragma unroll
        for (int j = 0; j < 4; j++) {
            alo[j] += xd * S[d * 32 + c0 + j];
            ahi[j] += xd * S[d * 32 + c0 + 16 + j];
        }
    }
    float4 flo, fhi;
    flo.x = fmaxf(alo[0], 0.f); flo.y = fmaxf(alo[1], 0.f);
    flo.z = fmaxf(alo[2], 0.f); flo.w = fmaxf(alo[3], 0.f);
    fhi.x = fmaxf(ahi[0], 0.f); fhi.y = fmaxf(ahi[1], 0.f);
    fhi.z = fmaxf(ahi[2], 0.f); fhi.w = fmaxf(ahi[3], 0.f);
    *(float4*)(out + (size_t)v * 64 + 32 + c0) = flo;
    *(float4*)(out + (size_t)v * 64 + 32 + c0 + 16) = fhi;
}

extern "C" void kernel_launch(void* const* d_in, const int* in_sizes, int n_in,
                              void* d_out, int out_size, void* d_ws, size_t ws_size,
                              hipStream_t stream) {
    const float* feat      = (const float*)d_in[0];
    const float* embed     = (const float*)d_in[1];
    const float* transform = (const float*)d_in[2];
    const float* weight    = (const float*)d_in[3];
    const float* w_comp    = (const float*)d_in[4];
    const float* self_w    = (const float*)d_in[5];
    const float* A_w       = (const float*)d_in[6];
    const float* A_b       = (const float*)d_in[7];
    const float* B_w       = (const float*)d_in[8];
    const float* B_b       = (const float*)d_in[9];
    const float* attn_emb  = (const float*)d_in[10];
    const int*   idx       = (const int*)d_in[11];
    const int*   edge_src  = (const int*)d_in[12];
    const int*   edge_dst  = (const int*)d_in[13];
    const int*   edge_type = (const int*)d_in[14];
    float* out = (float*)d_out;

    // -------- workspace layout (~72 MB of 256 MiB; fill cost is constant) ----
    char* ws = (char*)d_ws;
    int2*           ebuf    = (int2*)ws;                                    // 6.4 MB
    int2*           ebuf2   = (int2*)(ws + (size_t)NE * 8);                 // 6.4 MB
    unsigned short* init_bf = (unsigned short*)(ws + (size_t)NE * 16);      // 3.2 MB
    unsigned short* wfragB  = (unsigned short*)((char*)init_bf + 3200000);  // 8 KB
    unsigned short* afrag   = (unsigned short*)((char*)wfragB + 8192);      // 4 KB
    float*          aproj   = (float*)((char*)afrag + 4096);                // 2 KB
    int*            cpb_t   = (int*)((char*)aproj + 2048);                  // 800 KB
    int*            boff    = cpb_t + NBC * 256;                            // NBC+1
    int*            row_off = boff + NBC + 1;                               // NBC*64+1
    unsigned int*   amsg    = (unsigned int*)(row_off + NBC * 64 + 64);     // 51.2 MB

    k_phase1<<<212 + ABLK, 256, 0, stream>>>(feat, embed, transform, idx, weight,
                                             A_w, A_b, attn_emb, edge_dst,
                                             out, init_bf, wfragB, afrag, aproj, cpb_t);
    k_scanB<<<1, 1024, 0, stream>>>(cpb_t, boff);
    k_scatB<<<ABLK, 256, 0, stream>>>(edge_src, edge_dst, edge_type, cpb_t, boff, ebuf);
    k_fine<<<NBC, 256, 0, stream>>>(boff, ebuf, ebuf2, row_off);
    k_msg<<<NE / 128, 256, 0, stream>>>(ebuf2, wfragB, afrag, aproj, w_comp,
                                        B_w, B_b, init_bf, amsg);
    k_agg<<<NBC, 256, 0, stream>>>(row_off, amsg, self_w, out);
}